// Round 1
// baseline (172.247 us; speedup 1.0000x reference)
//
#include <hip/hip_runtime.h>

#define L_SEQ 2048
#define F_DIM 128
#define U_DIM 32
#define QT 4
#define KT 64
#define AW_HALF 32
#define LOG2E 1.4426950408889634f

// ---------------- kernel 1: qv = x@Wt + bh, kv = x@Wx ----------------
__global__ __launch_bounds__(256) void prep_kernel(
    const float* __restrict__ inp,   // [L][F]
    const float* __restrict__ Wt,    // [F][U]
    const float* __restrict__ Wx,    // [F][U]
    const float* __restrict__ bh,    // [U]
    float* __restrict__ qv,          // [L][U]
    float* __restrict__ kv) {        // [L][U]
  int t = blockIdx.x * 256 + threadIdx.x;   // 0 .. L*U-1
  int row = t >> 5;
  int u = t & 31;
  const float* xr = inp + row * F_DIM;
  float aq = bh[u];
  float ak = 0.0f;
#pragma unroll 8
  for (int f = 0; f < F_DIM; ++f) {
    float x = xr[f];
    aq = fmaf(x, Wt[f * U_DIM + u], aq);
    ak = fmaf(x, Wx[f * U_DIM + u], ak);
  }
  qv[row * U_DIM + u] = aq;
  kv[row * U_DIM + u] = ak;
}

// ---------------- kernel 2: fused scores + softmax + PV ----------------
template <bool CLAMP>
__device__ __forceinline__ void phase_b(float (&acc)[QT][2],
                                        const float (*s_w)[KT],
                                        const float* __restrict__ x,
                                        int k0, int ks, int f2) {
#pragma unroll
  for (int g = 0; g < 4; ++g) {
    const int jb = ks * 16 + g * 4;
    float4 w4[QT];
#pragma unroll
    for (int q = 0; q < QT; ++q)
      w4[q] = *reinterpret_cast<const float4*>(&s_w[q][jb]);
#pragma unroll
    for (int jj = 0; jj < 4; ++jj) {
      int k = k0 + jb + jj;
      if (CLAMP) k = min(k, L_SEQ - 1);   // OOB keys have w==0; clamp keeps load in-bounds
      float2 xv = *reinterpret_cast<const float2*>(&x[k * F_DIM + 2 * f2]);
#pragma unroll
      for (int q = 0; q < QT; ++q) {
        float wq = reinterpret_cast<const float*>(&w4[q])[jj];
        acc[q][0] = fmaf(wq, xv.x, acc[q][0]);
        acc[q][1] = fmaf(wq, xv.y, acc[q][1]);
      }
    }
  }
}

__global__ __launch_bounds__(256) void attn_kernel(
    const float* __restrict__ x,     // [L][F]
    const float* __restrict__ qv,    // [L][U] (bh folded in)
    const float* __restrict__ kv,    // [L][U]
    const float* __restrict__ Wa,    // [U]
    const float* __restrict__ ba,    // [1]
    float* __restrict__ out) {       // [L][F]
  __shared__ float s_kv[KT][U_DIM + 1];    // +1 pad: conflict-free row reads
  __shared__ float s_w[QT][KT];
  __shared__ float s_red[4][QT][F_DIM];
  __shared__ float s_den[QT];

  const int tid = threadIdx.x;
  const int q0 = blockIdx.x * QT;
  const int lo = max(0, q0 - AW_HALF);

  const int qa = tid >> 6;   // phase A: this thread's query (== wave id)
  const int ka = tid & 63;   // phase A: this thread's key within tile
  const int ks = qa;         // phase B: k-quarter
  const int f2 = ka;         // phase B: f-pair index

  float qreg[U_DIM];
#pragma unroll
  for (int u = 0; u < U_DIM; ++u) qreg[u] = qv[(q0 + qa) * U_DIM + u];

  float wa[U_DIM];           // uniform -> expect s_load into SGPRs
#pragma unroll
  for (int u = 0; u < U_DIM; ++u) wa[u] = Wa[u];
  const float ba0 = ba[0];

  float acc[QT][2];
#pragma unroll
  for (int q = 0; q < QT; ++q) { acc[q][0] = 0.0f; acc[q][1] = 0.0f; }
  float dreg = 0.0f;

  const int kmin = q0 + qa - AW_HALF;   // reference penalty: w=0 iff k < q-32

  for (int k0 = lo; k0 < L_SEQ; k0 += KT) {
    // ---- stage kv tile (coalesced global, padded LDS) ----
#pragma unroll
    for (int i = 0; i < (KT * U_DIM) / 256; ++i) {
      int idx = tid + i * 256;
      int kr = idx >> 5;
      int uu = idx & 31;
      int kg = k0 + kr;
      s_kv[kr][uu] = (kg < L_SEQ) ? kv[kg * U_DIM + uu] : 0.0f;
    }
    __syncthreads();

    // ---- phase A: one (q,k) score per thread ----
    {
      int k = k0 + ka;
      float s = ba0;
#pragma unroll
      for (int u = 0; u < U_DIM; ++u) {
        float tv = qreg[u] + s_kv[ka][u];
        // tanh(tv) = sign(tv) * (1-z)/(1+z), z = e^{-2|tv|}
        float m = tv * (2.0f * LOG2E);
        float z = __builtin_amdgcn_exp2f(-__builtin_fabsf(m));
        float r = __builtin_amdgcn_rcpf(1.0f + z);
        float th = fmaf(-2.0f * z, r, 1.0f);
        th = __builtin_copysignf(th, tv);
        s = fmaf(wa[u], th, s);
      }
      // e = sigmoid(s); w = exp(e)  (e in (0,1): no overflow, no online max needed)
      float sg = __builtin_amdgcn_rcpf(1.0f + __builtin_amdgcn_exp2f(-s * LOG2E));
      float w = __builtin_amdgcn_exp2f(sg * LOG2E);
      if (k >= L_SEQ || k < kmin) w = 0.0f;   // penalized keys: exactly 0 (matches fp32 underflow)
      s_w[qa][ka] = w;
      dreg += w;
    }
    __syncthreads();

    // ---- phase B: acc[q][f-pair] += w[q][k] * x[k][f] over this thread's k-quarter ----
    if (k0 + KT <= L_SEQ) phase_b<false>(acc, s_w, x, k0, ks, f2);
    else                  phase_b<true>(acc, s_w, x, k0, ks, f2);
    // no barrier needed here: next staging touches only s_kv; s_w rewritten after next sync
  }

  // ---- epilogue: den wave-reduce + k-quarter reduction + divide ----
  float d = dreg;
#pragma unroll
  for (int off = 1; off < 64; off <<= 1) d += __shfl_xor(d, off, 64);
  if (ka == 0) s_den[qa] = d;

#pragma unroll
  for (int q = 0; q < QT; ++q) {
    s_red[ks][q][2 * f2]     = acc[q][0];
    s_red[ks][q][2 * f2 + 1] = acc[q][1];
  }
  __syncthreads();

#pragma unroll
  for (int rep = 0; rep < 2; ++rep) {
    int o = tid + rep * 256;
    int q = o >> 7;
    int f = o & 127;
    float num = s_red[0][q][f] + s_red[1][q][f] + s_red[2][q][f] + s_red[3][q][f];
    out[(q0 + q) * F_DIM + f] = num / s_den[q];
  }
}

extern "C" void kernel_launch(void* const* d_in, const int* in_sizes, int n_in,
                              void* d_out, int out_size, void* d_ws, size_t ws_size,
                              hipStream_t stream) {
  (void)in_sizes; (void)n_in; (void)out_size; (void)ws_size;
  const float* inp = (const float*)d_in[0];
  const float* Wt  = (const float*)d_in[1];
  const float* Wx  = (const float*)d_in[2];
  const float* bh  = (const float*)d_in[3];
  const float* Wa  = (const float*)d_in[4];
  const float* ba  = (const float*)d_in[5];
  float* outp = (float*)d_out;

  float* qv = (float*)d_ws;                 // L*U floats
  float* kv = qv + L_SEQ * U_DIM;           // L*U floats (512 KB total ws)

  prep_kernel<<<(L_SEQ * U_DIM) / 256, 256, 0, stream>>>(inp, Wt, Wx, bh, qv, kv);
  attn_kernel<<<L_SEQ / QT, 256, 0, stream>>>(inp, qv, kv, Wa, ba, outp);
}

// Round 6
// 135.879 us; speedup vs baseline: 1.2677x; 1.2677x over previous
//
#include <hip/hip_runtime.h>

#define L_SEQ 2048
#define F_DIM 128
#define U_DIM 32
#define AW_HALF 32
#define LOG2E 1.4426950408889634f
#define SC2 (2.0f * LOG2E)
#define NTILE (L_SEQ / 64)

// ---------------- kernel 1: qv2 = (x@Wt + bh)*2log2e, kv2 = (x@Wx)*2log2e ----
// One wave per row; lanes 0-31 do Wt (u=lane), lanes 32-63 do Wx.
__global__ __launch_bounds__(256) void prep_kernel(
    const float* __restrict__ x,     // [L][F]
    const float* __restrict__ Wt,    // [F][U]
    const float* __restrict__ Wx,    // [F][U]
    const float* __restrict__ bh,    // [U]
    float* __restrict__ qv2,         // [L][U]
    float* __restrict__ kv2) {       // [L][U]
  const int w = threadIdx.x >> 6;
  const int lane = threadIdx.x & 63;
  const int r = blockIdx.x * 4 + w;
  const int h = lane >> 5;           // 0 -> Wt/qv2, 1 -> Wx/kv2
  const int u = lane & 31;
  const float* W = h ? Wx : Wt;
  const float* xr = x + r * F_DIM;   // uniform per wave -> s_loads
  float acc = h ? 0.0f : bh[u];
#pragma unroll 16
  for (int f = 0; f < F_DIM; ++f)
    acc = fmaf(xr[f], W[f * U_DIM + u], acc);
  acc *= SC2;
  if (h == 0) qv2[r * U_DIM + u] = acc;
  else        kv2[r * U_DIM + u] = acc;
}

// ---------------- kernel 2: fused scores + softmax + PV, barrier-free ------
__global__ __launch_bounds__(256, 4) void attn_kernel(
    const float* __restrict__ x,     // [L][F]
    const float* __restrict__ qv2,   // [L][U]
    const float* __restrict__ kv2,   // [L][U]
    const float* __restrict__ Wa,    // [U]
    const float* __restrict__ ba,    // [1]
    float* __restrict__ out) {       // [L][F]
  __shared__ float s_w[4][2][64];    // [wave][parity][key] - per-wave, no aliasing
  __shared__ float s_red[4][F_DIM];
  __shared__ float s_den[4];

  const int tid = threadIdx.x;
  const int w = tid >> 6;            // wave id = k-chunk
  const int lane = tid & 63;
  const int q = blockIdx.x;

  // wave-uniform loads -> SGPRs
  const float* qrow = qv2 + q * U_DIM;
  float qs[U_DIM], was[U_DIM];
#pragma unroll
  for (int u = 0; u < U_DIM; ++u) qs[u] = qrow[u];
#pragma unroll
  for (int u = 0; u < U_DIM; ++u) was[u] = Wa[u];
  float base = ba[0];
#pragma unroll
  for (int u = 0; u < U_DIM; ++u) base += was[u];   // s = base - 2*sum(wa*r)

  const int kmin = q - AW_HALF;                     // w=0 iff k < q-32
  const int t0 = (kmin > 0 ? kmin : 0) >> 6;

  const int kg = lane >> 5;          // PV: k-half within tile
  const int fl = lane & 31;          // PV: f-quad owner (cols 4fl..4fl+3)

  float acc[4] = {0.0f, 0.0f, 0.0f, 0.0f};
  float dreg = 0.0f;

  for (int t = t0 + w; t < NTILE; t += 4) {
    const int k0 = t * 64;
    const int p = (t >> 2) & 1;

    // ---- score: this lane's key = k0 + lane ----
    const float* kr = kv2 + (size_t)(k0 + lane) * U_DIM;
    float4 kvv[8];
#pragma unroll
    for (int c = 0; c < 8; ++c)
      kvv[c] = *reinterpret_cast<const float4*>(kr + 4 * c);

    float sacc = 0.0f;
#pragma unroll
    for (int u = 0; u < U_DIM; ++u) {
      // m = 2*log2e*(qv+kv+bh); tanh = 1 - 2*rcp(exp2(m)+1)
      float m = qs[u] + reinterpret_cast<const float*>(kvv)[u];
      float E = __builtin_amdgcn_exp2f(m);
      float r = __builtin_amdgcn_rcpf(E + 1.0f);
      sacc = fmaf(was[u], r, sacc);
    }
    float s = fmaf(-2.0f, sacc, base);
    float e = __builtin_amdgcn_rcpf(1.0f + __builtin_amdgcn_exp2f(-s * LOG2E));
    float wgt = __builtin_amdgcn_exp2f(e * LOG2E);   // exp(sigmoid(s)) in (1, e)
    if (k0 + lane < kmin) wgt = 0.0f;                // penalized: exact 0 (matches fp32 underflow)
    s_w[w][p][lane] = wgt;
    dreg += wgt;
    // make all 64 lanes' writes visible to this wave (wave-synchronous, no barrier)
    asm volatile("s_waitcnt lgkmcnt(0)" ::: "memory");

    // ---- PV: acc[j] += w[k] * x[k][4fl+j] over this lane's k-half ----
#pragma unroll
    for (int c = 0; c < 8; ++c) {
      float4 w4 = *reinterpret_cast<const float4*>(&s_w[w][p][kg * 32 + 4 * c]);
#pragma unroll
      for (int j = 0; j < 4; ++j) {
        const float* xr = x + (size_t)(k0 + kg * 32 + 4 * c + j) * F_DIM + 4 * fl;
        float4 x4 = *reinterpret_cast<const float4*>(xr);
        float wj = reinterpret_cast<const float*>(&w4)[j];
        acc[0] = fmaf(wj, x4.x, acc[0]);
        acc[1] = fmaf(wj, x4.y, acc[1]);
        acc[2] = fmaf(wj, x4.z, acc[2]);
        acc[3] = fmaf(wj, x4.w, acc[3]);
      }
    }
  }

  // ---- reduce: k-halves via shuffle, waves via LDS ----
#pragma unroll
  for (int i = 0; i < 4; ++i) acc[i] += __shfl_xor(acc[i], 32);
#pragma unroll
  for (int off = 1; off < 64; off <<= 1) dreg += __shfl_xor(dreg, off);

  if (lane < 32)
    *reinterpret_cast<float4*>(&s_red[w][4 * fl]) = *reinterpret_cast<float4*>(acc);
  if (lane == 0) s_den[w] = dreg;
  __syncthreads();

  if (tid < F_DIM) {
    float den = s_den[0] + s_den[1] + s_den[2] + s_den[3];
    float num = s_red[0][tid] + s_red[1][tid] + s_red[2][tid] + s_red[3][tid];
    out[(size_t)q * F_DIM + tid] = num / den;
  }
}

extern "C" void kernel_launch(void* const* d_in, const int* in_sizes, int n_in,
                              void* d_out, int out_size, void* d_ws, size_t ws_size,
                              hipStream_t stream) {
  (void)in_sizes; (void)n_in; (void)out_size; (void)ws_size;
  const float* inp = (const float*)d_in[0];
  const float* Wt  = (const float*)d_in[1];
  const float* Wx  = (const float*)d_in[2];
  const float* bh  = (const float*)d_in[3];
  const float* Wa  = (const float*)d_in[4];
  const float* ba  = (const float*)d_in[5];
  float* outp = (float*)d_out;

  float* qv2 = (float*)d_ws;                 // L*U floats
  float* kv2 = qv2 + L_SEQ * U_DIM;          // L*U floats

  prep_kernel<<<L_SEQ / 4, 256, 0, stream>>>(inp, Wt, Wx, bh, qv2, kv2);
  attn_kernel<<<L_SEQ, 256, 0, stream>>>(inp, qv2, kv2, Wa, ba, outp);
}

// Round 12
// 134.583 us; speedup vs baseline: 1.2799x; 1.0096x over previous
//
#include <hip/hip_runtime.h>

#define L_SEQ 2048
#define F_DIM 128
#define U_DIM 32
#define AW_HALF 32
#define LOG2E 1.4426950408889634f
#define SC2 (2.0f * LOG2E)
#define NTILE 32      // 2048 / 64 keys per tile
#define NGRP 512      // query groups of 4
#define QPB 4         // queries per block

// ---------------- kernel 1: qv2 = (x@Wt + bh)*2log2e, kv2 = (x@Wx)*2log2e ----
__global__ __launch_bounds__(256) void prep_kernel(
    const float* __restrict__ x, const float* __restrict__ Wt,
    const float* __restrict__ Wx, const float* __restrict__ bh,
    float* __restrict__ qv2, float* __restrict__ kv2) {
  const int w = threadIdx.x >> 6;
  const int lane = threadIdx.x & 63;
  const int r = blockIdx.x * 4 + w;
  const int h = lane >> 5;
  const int u = lane & 31;
  const float* W = h ? Wx : Wt;
  const float* xr = x + r * F_DIM;
  float acc = h ? 0.0f : bh[u];
#pragma unroll 16
  for (int f = 0; f < F_DIM; ++f)
    acc = fmaf(xr[f], W[f * U_DIM + u], acc);
  acc *= SC2;
  if (h == 0) qv2[r * U_DIM + u] = acc;
  else        kv2[r * U_DIM + u] = acc;
}

// async global->LDS, 16B per lane (dest = wave-uniform base + lane*16)
__device__ __forceinline__ void load_lds16(const float* gsrc, float* ldst) {
  __builtin_amdgcn_global_load_lds(
      (const __attribute__((address_space(1))) void*)gsrc,
      (__attribute__((address_space(3))) void*)ldst, 16, 0, 0);
}

// ---------------- kernel 2: 4 queries/block, shared x tile, T14 pipeline ----
__global__ __launch_bounds__(256, 4) void attn_kernel(
    const float* __restrict__ x,     // [L][F]
    const float* __restrict__ qv2,   // [L][U]
    const float* __restrict__ kv2,   // [L][U]
    const float* __restrict__ Wa,    // [U]
    const float* __restrict__ ba,    // [1]
    float* __restrict__ pnum,        // [2*L][F] partials (phase-major)
    float* __restrict__ pden) {      // [2*L]
  __shared__ __align__(16) float s_x[64 * F_DIM];   // 32 KB x tile (aliased as s_red in epilogue)
  __shared__ __align__(16) float s_wT[64 * QPB];    // [key][query] weights
  __shared__ float s_dn[QPB];

  const int tid = threadIdx.x;
  const int w = tid >> 6;
  const int lane = tid & 63;
  const int wu = __builtin_amdgcn_readfirstlane(w);  // SGPR wave id -> s_loads for qs

  // grid remap: CU i gets groups {i, 511-i} x phases {0,1} -> ~constant work per CU
  const int bi = blockIdx.x & 255;
  const int bj = blockIdx.x >> 8;                    // 0..3
  const int g = (bj & 1) ? (NGRP - 1 - bi) : bi;
  const int p = bj >> 1;
  const int q0 = g * QPB;

  const int myq = q0 + wu;
  const int kmin = myq - AW_HALF;                    // w=0 iff k < q-32 (no upper cutoff)
  const int t0b = (q0 > AW_HALF) ? ((q0 - AW_HALF) >> 6) : 0;
  const int t0p = t0b + p;                           // this phase: tiles t0p, t0p+2, ...
  const int nt = (t0p < NTILE) ? ((NTILE - t0p + 1) >> 1) : 0;

  // wave-uniform -> SGPRs
  const float* qrow = qv2 + (size_t)myq * U_DIM;
  float qs[U_DIM], was[U_DIM];
#pragma unroll
  for (int u = 0; u < U_DIM; ++u) qs[u] = qrow[u];
#pragma unroll
  for (int u = 0; u < U_DIM; ++u) was[u] = Wa[u];
  float base = ba[0];
#pragma unroll
  for (int u = 0; u < U_DIM; ++u) base += was[u];    // s = base - 2*sum(wa*rcp)

  const int fq = lane & 31;                          // PV: f-quad 4fq..4fq+3
  const int kq = lane >> 5;                          // PV: key-octet selector

  float acc[QPB][4];
#pragma unroll
  for (int q = 0; q < QPB; ++q)
#pragma unroll
    for (int jj = 0; jj < 4; ++jj) acc[q][jj] = 0.0f;
  float dreg = 0.0f;
  float4 kvv[8];

  // prologue: kv loads FIRST (score can start without waiting the stage)
  if (nt > 0) {
    const float* kr = kv2 + (size_t)(t0p * 64 + lane) * U_DIM;
#pragma unroll
    for (int c = 0; c < 8; ++c) kvv[c] = *reinterpret_cast<const float4*>(kr + 4 * c);
#pragma unroll
    for (int s = 0; s < 8; ++s) {
      const int off = s * 1024 + wu * 256;           // floats; wave-uniform LDS base
      load_lds16(x + (size_t)t0p * (64 * F_DIM) + off + lane * 4, s_x + off);
    }
  }

  int tcur = t0p;
  for (int it = 0; it < nt; ++it) {
    const bool more = (it + 1 < nt);
    const int tnext = more ? tcur + 2 : tcur;        // dummy reload on last iter keeps vmcnt uniform
    const int k0 = tcur * 64;

    // ---- a) score(tcur) from kvv regs (hides the in-flight x stage) ----
    const float* kvf = reinterpret_cast<const float*>(kvv);
    float sacc = 0.0f;
#pragma unroll
    for (int u = 0; u < U_DIM; ++u) {
      float m = qs[u] + kvf[u];                      // 2log2e*(q+k+bh)
      float E = __builtin_amdgcn_exp2f(m);
      float r = __builtin_amdgcn_rcpf(E + 1.0f);     // tanh = 1 - 2r
      sacc = fmaf(was[u], r, sacc);
    }
    float s = fmaf(-2.0f, sacc, base);
    float e = __builtin_amdgcn_rcpf(1.0f + __builtin_amdgcn_exp2f(-s * LOG2E));
    float wgt = __builtin_amdgcn_exp2f(e * LOG2E);   // exp(sigmoid(s))
    if (k0 + lane < kmin) wgt = 0.0f;                // penalized: exact 0 (== fp32 underflow)
    s_wT[lane * QPB + wu] = wgt;
    dreg += wgt;

    // ---- c) prefetch kv(tnext) into kvv (in flight across the barrier) ----
    {
      const float* kr = kv2 + (size_t)(tnext * 64 + lane) * U_DIM;
#pragma unroll
      for (int c = 0; c < 8; ++c) kvv[c] = *reinterpret_cast<const float4*>(kr + 4 * c);
    }

    // ---- d) stage(tcur) done (8 kv loads remain in flight), s_wT visible ----
    asm volatile("s_waitcnt lgkmcnt(0)" ::: "memory");
    asm volatile("s_waitcnt vmcnt(8)" ::: "memory");
    __builtin_amdgcn_s_barrier();
    asm volatile("" ::: "memory");

    // ---- f) PV(tcur): each wave reads x ONCE for all 4 queries ----
    const int kbase = 16 * w + 8 * kq;               // wave owns keys [16w,16w+16)
#pragma unroll
    for (int ii = 0; ii < 8; ++ii) {
      const int kl = kbase + ii;
      float4 wv = *reinterpret_cast<const float4*>(s_wT + kl * QPB);  // broadcast
      float4 xv = *reinterpret_cast<const float4*>(s_x + kl * F_DIM + fq * 4);
      acc[0][0] = fmaf(wv.x, xv.x, acc[0][0]);
      acc[0][1] = fmaf(wv.x, xv.y, acc[0][1]);
      acc[0][2] = fmaf(wv.x, xv.z, acc[0][2]);
      acc[0][3] = fmaf(wv.x, xv.w, acc[0][3]);
      acc[1][0] = fmaf(wv.y, xv.x, acc[1][0]);
      acc[1][1] = fmaf(wv.y, xv.y, acc[1][1]);
      acc[1][2] = fmaf(wv.y, xv.z, acc[1][2]);
      acc[1][3] = fmaf(wv.y, xv.w, acc[1][3]);
      acc[2][0] = fmaf(wv.z, xv.x, acc[2][0]);
      acc[2][1] = fmaf(wv.z, xv.y, acc[2][1]);
      acc[2][2] = fmaf(wv.z, xv.z, acc[2][2]);
      acc[2][3] = fmaf(wv.z, xv.w, acc[2][3]);
      acc[3][0] = fmaf(wv.w, xv.x, acc[3][0]);
      acc[3][1] = fmaf(wv.w, xv.y, acc[3][1]);
      acc[3][2] = fmaf(wv.w, xv.z, acc[3][2]);
      acc[3][3] = fmaf(wv.w, xv.w, acc[3][3]);
    }

    // ---- g) all waves done reading s_x ----
    asm volatile("s_waitcnt lgkmcnt(0)" ::: "memory");
    __builtin_amdgcn_s_barrier();
    asm volatile("" ::: "memory");

    // ---- h) stage x(tnext) (hidden under next score) ----
    if (more) {
#pragma unroll
      for (int s = 0; s < 8; ++s) {
        const int off = s * 1024 + wu * 256;
        load_lds16(x + (size_t)tnext * (64 * F_DIM) + off + lane * 4, s_x + off);
      }
    }
    tcur = tnext;
  }

  // ---- epilogue: reduce + write partials ----
#pragma unroll
  for (int q = 0; q < QPB; ++q)
#pragma unroll
    for (int jj = 0; jj < 4; ++jj) acc[q][jj] += __shfl_xor(acc[q][jj], 32);
#pragma unroll
  for (int off = 1; off < 64; off <<= 1) dreg += __shfl_xor(dreg, off);

  __syncthreads();                                   // safe to alias s_x as s_red
  float* s_red = s_x;                                // [wave][q][f] = w*512 + q*128 + f
  if (lane < 32) {
#pragma unroll
    for (int q = 0; q < QPB; ++q) {
      float4 v = make_float4(acc[q][0], acc[q][1], acc[q][2], acc[q][3]);
      *reinterpret_cast<float4*>(s_red + w * 512 + q * 128 + fq * 4) = v;
    }
  }
  if (lane == 0) s_dn[w] = dreg;
  __syncthreads();

  const int pq0 = p * L_SEQ + q0;
#pragma unroll
  for (int r = 0; r < 2; ++r) {
    const int o = tid + r * 256;
    const int qi = o >> 7, f = o & 127;
    float v = s_red[0 * 512 + qi * 128 + f] + s_red[1 * 512 + qi * 128 + f] +
              s_red[2 * 512 + qi * 128 + f] + s_red[3 * 512 + qi * 128 + f];
    pnum[(size_t)(pq0 + qi) * F_DIM + f] = v;
  }
  if (tid < QPB) pden[pq0 + tid] = s_dn[tid];
}

// ---------------- kernel 3: combine 2 phase-partials + divide ----------------
__global__ __launch_bounds__(256) void combine_kernel(
    const float* __restrict__ pnum, const float* __restrict__ pden,
    float* __restrict__ out) {
  const int o = blockIdx.x * 256 + threadIdx.x;      // 0 .. 2048*128-1
  const int q = o >> 7;
  float num = pnum[o] + pnum[(size_t)L_SEQ * F_DIM + o];
  float den = pden[q] + pden[L_SEQ + q];
  out[o] = num / den;
}

extern "C" void kernel_launch(void* const* d_in, const int* in_sizes, int n_in,
                              void* d_out, int out_size, void* d_ws, size_t ws_size,
                              hipStream_t stream) {
  (void)in_sizes; (void)n_in; (void)out_size; (void)ws_size;
  const float* inp = (const float*)d_in[0];
  const float* Wt  = (const float*)d_in[1];
  const float* Wx  = (const float*)d_in[2];
  const float* bh  = (const float*)d_in[3];
  const float* Wa  = (const float*)d_in[4];
  const float* ba  = (const float*)d_in[5];
  float* outp = (float*)d_out;

  float* qv2  = (float*)d_ws;                        // L*U
  float* kv2  = qv2 + L_SEQ * U_DIM;                 // L*U
  float* pnum = kv2 + L_SEQ * U_DIM;                 // 2*L*F
  float* pden = pnum + 2 * L_SEQ * F_DIM;            // 2*L

  prep_kernel<<<L_SEQ / 4, 256, 0, stream>>>(inp, Wt, Wx, bh, qv2, kv2);
  attn_kernel<<<2 * NGRP, 256, 0, stream>>>(inp, qv2, kv2, Wa, ba, pnum, pden);
  combine_kernel<<<(L_SEQ * F_DIM) / 256, 256, 0, stream>>>(pnum, pden, outp);
}

// Round 13
// 106.993 us; speedup vs baseline: 1.6099x; 1.2579x over previous
//
#include <hip/hip_runtime.h>

#define L_SEQ 2048
#define F_DIM 128
#define U_DIM 32
#define LOG2E 1.4426950408889634f
#define SC2 (2.0f * LOG2E)
#define NTILE 32     // 2048 / 64 keys
#define NPAIR 256    // pair-blocks: (group g, group 511-g), 4 queries each
#define NPH 16       // 16 phase-waves per block (1024 threads)

// ---------------- kernel 1: qv2 = (x@Wt + bh)*2log2e, kv2 = (x@Wx)*2log2e ----
__global__ __launch_bounds__(256) void prep_kernel(
    const float* __restrict__ x, const float* __restrict__ Wt,
    const float* __restrict__ Wx, const float* __restrict__ bh,
    float* __restrict__ qv2, float* __restrict__ kv2) {
  const int w = threadIdx.x >> 6;
  const int lane = threadIdx.x & 63;
  const int r = blockIdx.x * 4 + w;
  const int h = lane >> 5;
  const int u = lane & 31;
  const float* W = h ? Wx : Wt;
  const float* xr = x + r * F_DIM;
  float acc = h ? 0.0f : bh[u];
#pragma unroll 16
  for (int f = 0; f < F_DIM; ++f)
    acc = fmaf(xr[f], W[f * U_DIM + u], acc);
  acc *= SC2;
  if (h == 0) qv2[r * U_DIM + u] = acc;
  else        kv2[r * U_DIM + u] = acc;
}

// ---------------- kernel 2: pair-block, 16 balanced waves, barrier-free ----
__global__ __launch_bounds__(1024, 4) void attn_kernel(
    const float* __restrict__ x,     // [L][F]
    const float* __restrict__ qv2,   // [L][U]
    const float* __restrict__ kv2,   // [L][U]
    const float* __restrict__ Wa,    // [U]
    const float* __restrict__ ba,    // [1]
    float* __restrict__ out) {       // [L][F]
  // main loop: per-wave private w-slices s_mem[w*512 .. +512) = [2 quads][64 keys][4 q]
  // epilogue (after syncthreads): s_mem[w*1024 .. +1024) = per-wave acc [8 q][128 f]
  __shared__ __align__(16) float s_mem[NPH * 1024];   // 64 KB
  __shared__ float s_dn[NPH][8];

  const int tid = threadIdx.x;
  const int w = tid >> 6;
  const int lane = tid & 63;
  const int pair = blockIdx.x;
  const int q0_lo = pair * 4;
  const int q0_hi = (2 * NPAIR - 1 - pair) * 4;          // (511 - pair)*4
  const int t0_lo = (q0_lo > 32) ? ((q0_lo - 32) >> 6) : 0;
  const int t0_hi = (q0_hi - 32) >> 6;                   // q0_hi >= 1024

  // wave-uniform -> SGPRs
  float was[U_DIM];
#pragma unroll
  for (int u = 0; u < U_DIM; ++u) was[u] = Wa[u];
  float base = ba[0];
#pragma unroll
  for (int u = 0; u < U_DIM; ++u) base += was[u];        // s = base - 2*sum(wa*rcp)

  float* wsl = s_mem + w * 512;

  const int kq = lane >> 5;          // PV: key-half
  const int fq = lane & 31;          // PV: f-quad (4fq..4fq+3)

  float4 accL[4], accH[4];
#pragma unroll
  for (int qi = 0; qi < 4; ++qi) {
    accL[qi] = make_float4(0.f, 0.f, 0.f, 0.f);
    accH[qi] = make_float4(0.f, 0.f, 0.f, 0.f);
  }
  float dreg[8];
#pragma unroll
  for (int i = 0; i < 8; ++i) dreg[i] = 0.f;

  for (int t = t0_lo + w; t < NTILE; t += NPH) {
    const int k0 = t * 64;
    const bool hi_on = (t >= t0_hi);                     // wave-uniform

    // kv for this lane's key (shared by all 8 queries)
    const float* kr = kv2 + (size_t)(k0 + lane) * U_DIM;
    float4 kvv[8];
#pragma unroll
    for (int c = 0; c < 8; ++c) kvv[c] = *reinterpret_cast<const float4*>(kr + 4 * c);
    const float* kvf = reinterpret_cast<const float*>(kvv);

    // ---- score, lo quad (always) ----
#pragma unroll
    for (int qi = 0; qi < 4; ++qi) {
      const int q = q0_lo + qi;
      const float* qrow = qv2 + (size_t)q * U_DIM;       // uniform -> s_load
      float sacc = 0.f;
#pragma unroll
      for (int u = 0; u < U_DIM; ++u) {
        float m = qrow[u] + kvf[u];
        float E = __builtin_amdgcn_exp2f(m);
        float r = __builtin_amdgcn_rcpf(E + 1.0f);       // tanh = 1 - 2r
        sacc = fmaf(was[u], r, sacc);
      }
      float s = fmaf(-2.0f, sacc, base);
      float e = __builtin_amdgcn_rcpf(1.0f + __builtin_amdgcn_exp2f(-s * LOG2E));
      float wq = __builtin_amdgcn_exp2f(e * LOG2E);      // exp(sigmoid(s))
      if (k0 + lane < q - 32) wq = 0.f;                  // penalty: exact 0
      wsl[lane * 4 + qi] = wq;
      dreg[qi] += wq;
    }
    // ---- score, hi quad (only when its keys are unmasked) ----
    if (hi_on) {
#pragma unroll
      for (int qi = 0; qi < 4; ++qi) {
        const int q = q0_hi + qi;
        const float* qrow = qv2 + (size_t)q * U_DIM;
        float sacc = 0.f;
#pragma unroll
        for (int u = 0; u < U_DIM; ++u) {
          float m = qrow[u] + kvf[u];
          float E = __builtin_amdgcn_exp2f(m);
          float r = __builtin_amdgcn_rcpf(E + 1.0f);
          sacc = fmaf(was[u], r, sacc);
        }
        float s = fmaf(-2.0f, sacc, base);
        float e = __builtin_amdgcn_rcpf(1.0f + __builtin_amdgcn_exp2f(-s * LOG2E));
        float wq = __builtin_amdgcn_exp2f(e * LOG2E);
        if (k0 + lane < q - 32) wq = 0.f;
        wsl[256 + lane * 4 + qi] = wq;
        dreg[4 + qi] += wq;
      }
    }

    // wave-synchronous: all 64 lanes' ds_writes visible before ds_reads
    asm volatile("s_waitcnt lgkmcnt(0)" ::: "memory");

    // ---- PV: x read ONCE per tile, fma into both quads ----
    if (hi_on) {
#pragma unroll
      for (int ii = 0; ii < 32; ++ii) {
        const int kl = kq * 32 + ii;
        float4 xv = *reinterpret_cast<const float4*>(
            x + (size_t)(k0 + kl) * F_DIM + fq * 4);
        float4 wl = *reinterpret_cast<const float4*>(&wsl[kl * 4]);        // broadcast
        float4 wh = *reinterpret_cast<const float4*>(&wsl[256 + kl * 4]);  // broadcast
        accL[0].x = fmaf(wl.x, xv.x, accL[0].x); accL[0].y = fmaf(wl.x, xv.y, accL[0].y);
        accL[0].z = fmaf(wl.x, xv.z, accL[0].z); accL[0].w = fmaf(wl.x, xv.w, accL[0].w);
        accL[1].x = fmaf(wl.y, xv.x, accL[1].x); accL[1].y = fmaf(wl.y, xv.y, accL[1].y);
        accL[1].z = fmaf(wl.y, xv.z, accL[1].z); accL[1].w = fmaf(wl.y, xv.w, accL[1].w);
        accL[2].x = fmaf(wl.z, xv.x, accL[2].x); accL[2].y = fmaf(wl.z, xv.y, accL[2].y);
        accL[2].z = fmaf(wl.z, xv.z, accL[2].z); accL[2].w = fmaf(wl.z, xv.w, accL[2].w);
        accL[3].x = fmaf(wl.w, xv.x, accL[3].x); accL[3].y = fmaf(wl.w, xv.y, accL[3].y);
        accL[3].z = fmaf(wl.w, xv.z, accL[3].z); accL[3].w = fmaf(wl.w, xv.w, accL[3].w);
        accH[0].x = fmaf(wh.x, xv.x, accH[0].x); accH[0].y = fmaf(wh.x, xv.y, accH[0].y);
        accH[0].z = fmaf(wh.x, xv.z, accH[0].z); accH[0].w = fmaf(wh.x, xv.w, accH[0].w);
        accH[1].x = fmaf(wh.y, xv.x, accH[1].x); accH[1].y = fmaf(wh.y, xv.y, accH[1].y);
        accH[1].z = fmaf(wh.y, xv.z, accH[1].z); accH[1].w = fmaf(wh.y, xv.w, accH[1].w);
        accH[2].x = fmaf(wh.z, xv.x, accH[2].x); accH[2].y = fmaf(wh.z, xv.y, accH[2].y);
        accH[2].z = fmaf(wh.z, xv.z, accH[2].z); accH[2].w = fmaf(wh.z, xv.w, accH[2].w);
        accH[3].x = fmaf(wh.w, xv.x, accH[3].x); accH[3].y = fmaf(wh.w, xv.y, accH[3].y);
        accH[3].z = fmaf(wh.w, xv.z, accH[3].z); accH[3].w = fmaf(wh.w, xv.w, accH[3].w);
      }
    } else {
#pragma unroll
      for (int ii = 0; ii < 32; ++ii) {
        const int kl = kq * 32 + ii;
        float4 xv = *reinterpret_cast<const float4*>(
            x + (size_t)(k0 + kl) * F_DIM + fq * 4);
        float4 wl = *reinterpret_cast<const float4*>(&wsl[kl * 4]);
        accL[0].x = fmaf(wl.x, xv.x, accL[0].x); accL[0].y = fmaf(wl.x, xv.y, accL[0].y);
        accL[0].z = fmaf(wl.x, xv.z, accL[0].z); accL[0].w = fmaf(wl.x, xv.w, accL[0].w);
        accL[1].x = fmaf(wl.y, xv.x, accL[1].x); accL[1].y = fmaf(wl.y, xv.y, accL[1].y);
        accL[1].z = fmaf(wl.y, xv.z, accL[1].z); accL[1].w = fmaf(wl.y, xv.w, accL[1].w);
        accL[2].x = fmaf(wl.z, xv.x, accL[2].x); accL[2].y = fmaf(wl.z, xv.y, accL[2].y);
        accL[2].z = fmaf(wl.z, xv.z, accL[2].z); accL[2].w = fmaf(wl.z, xv.w, accL[2].w);
        accL[3].x = fmaf(wl.w, xv.x, accL[3].x); accL[3].y = fmaf(wl.w, xv.y, accL[3].y);
        accL[3].z = fmaf(wl.w, xv.z, accL[3].z); accL[3].w = fmaf(wl.w, xv.w, accL[3].w);
      }
    }
  }

  // ---- kq-half reduce + denominator wave-reduce ----
#pragma unroll
  for (int qi = 0; qi < 4; ++qi) {
    accL[qi].x += __shfl_xor(accL[qi].x, 32); accL[qi].y += __shfl_xor(accL[qi].y, 32);
    accL[qi].z += __shfl_xor(accL[qi].z, 32); accL[qi].w += __shfl_xor(accL[qi].w, 32);
    accH[qi].x += __shfl_xor(accH[qi].x, 32); accH[qi].y += __shfl_xor(accH[qi].y, 32);
    accH[qi].z += __shfl_xor(accH[qi].z, 32); accH[qi].w += __shfl_xor(accH[qi].w, 32);
  }
#pragma unroll
  for (int i = 0; i < 8; ++i) {
#pragma unroll
    for (int off = 1; off < 64; off <<= 1) dreg[i] += __shfl_xor(dreg[i], off);
  }
  if (lane == 0) {
#pragma unroll
    for (int i = 0; i < 8; ++i) s_dn[w][i] = dreg[i];
  }

  __syncthreads();   // all waves done with w-slices; safe to reuse s_mem

  if (lane < 32) {
#pragma unroll
    for (int qi = 0; qi < 4; ++qi) {
      *reinterpret_cast<float4*>(&s_mem[w * 1024 + qi * 128 + fq * 4]) = accL[qi];
      *reinterpret_cast<float4*>(&s_mem[w * 1024 + (4 + qi) * 128 + fq * 4]) = accH[qi];
    }
  }
  __syncthreads();

  // ---- final reduce over 16 waves + divide + store ----
  {
    const int qi = tid >> 7;          // 0..7
    const int f = tid & 127;
    float num = 0.f, den = 0.f;
#pragma unroll
    for (int ww = 0; ww < NPH; ++ww) {
      num += s_mem[ww * 1024 + tid];
      den += s_dn[ww][qi];
    }
    const int qg = (qi < 4) ? (q0_lo + qi) : (q0_hi + qi - 4);
    out[(size_t)qg * F_DIM + f] = num / den;
  }
}

extern "C" void kernel_launch(void* const* d_in, const int* in_sizes, int n_in,
                              void* d_out, int out_size, void* d_ws, size_t ws_size,
                              hipStream_t stream) {
  (void)in_sizes; (void)n_in; (void)out_size; (void)ws_size;
  const float* inp = (const float*)d_in[0];
  const float* Wt  = (const float*)d_in[1];
  const float* Wx  = (const float*)d_in[2];
  const float* bh  = (const float*)d_in[3];
  const float* Wa  = (const float*)d_in[4];
  const float* ba  = (const float*)d_in[5];
  float* outp = (float*)d_out;

  float* qv2 = (float*)d_ws;                 // L*U
  float* kv2 = qv2 + L_SEQ * U_DIM;          // L*U

  prep_kernel<<<L_SEQ / 4, 256, 0, stream>>>(inp, Wt, Wx, bh, qv2, kv2);
  attn_kernel<<<NPAIR, 1024, 0, stream>>>(inp, qv2, kv2, Wa, ba, outp);
}